// Round 6
// baseline (357.855 us; speedup 1.0000x reference)
//
#include <hip/hip_runtime.h>
#include <hip/hip_bf16.h>
#include <cstdint>

typedef __bf16 bf16x8 __attribute__((ext_vector_type(8)));
typedef float floatx4 __attribute__((ext_vector_type(4)));

__device__ __forceinline__ void gl2lds16(const void* g, void* l) {
  __builtin_amdgcn_global_load_lds(
      (const __attribute__((address_space(1))) unsigned int*)g,
      (__attribute__((address_space(3))) unsigned int*)(uintptr_t)l,
      16, 0, 0);
}

// ---------------- fp32 -> bf16 convert ----------------
__global__ __launch_bounds__(256)
void cvt_kernel(const float* __restrict__ in, __hip_bfloat16* __restrict__ out, int n) {
  int i = (blockIdx.x * 256 + threadIdx.x) * 4;
  if (i >= n) return;
  const float4 v = *(const float4*)(in + i);
  out[i + 0] = __float2bfloat16(v.x);
  out[i + 1] = __float2bfloat16(v.y);
  out[i + 2] = __float2bfloat16(v.z);
  out[i + 3] = __float2bfloat16(v.w);
}

// fused cvt of x (n0 elems) and w_qkv into one contiguous bf16 output
__global__ __launch_bounds__(256)
void cvt2_kernel(const float* __restrict__ in0, const float* __restrict__ in1,
                 __hip_bfloat16* __restrict__ out, int n0, int ntot) {
  int i = (blockIdx.x * 256 + threadIdx.x) * 4;
  if (i >= ntot) return;
  const float4 v = (i < n0) ? *(const float4*)(in0 + i)
                            : *(const float4*)(in1 + (i - n0));
  out[i + 0] = __float2bfloat16(v.x);
  out[i + 1] = __float2bfloat16(v.y);
  out[i + 2] = __float2bfloat16(v.z);
  out[i + 3] = __float2bfloat16(v.w);
}

#define MEMFENCE asm volatile("" ::: "memory")

// ======== QKV GEMM: 128x128 tile, 4 waves (2x2), 3-buffer counted-vmcnt ========
// BK=32, 3 LDS buffers (48KB -> 3 blocks/CU), depth-2 prefetch, vmcnt(4)
// counted wait + 1 barrier per K-step. XOR granule swizzle (R2-validated).
// XCD-aware bijective block swizzle (1536 % 8 == 0).
// Ledger: at step t top, outstanding = tiles {t,t+1} <= 8; vmcnt(4) => tile t
// landed; barrier => all waves' tile-t landed AND all t-1 reads retired =>
// staging t+2 into buf (t-1)%3 safe.
__global__ __launch_bounds__(256, 3)
void gemm_qkv128(const __hip_bfloat16* __restrict__ A,
                 const __hip_bfloat16* __restrict__ W,
                 __hip_bfloat16* __restrict__ Qr,
                 __hip_bfloat16* __restrict__ Kr,
                 __hip_bfloat16* __restrict__ Vt)
{
  extern __shared__ __hip_bfloat16 sm[];   // 49408 B: 3 x 16KB bufs + invf
  const int tid = threadIdx.x, lane = tid & 63, wave = tid >> 6;
  const int wr = wave >> 1, wc = wave & 1;
  const int bid = blockIdx.y * 32 + blockIdx.x;          // 32 x 48 grid
  const int swz = (bid & 7) * 192 + (bid >> 3);          // bijective (1536%8==0)
  const int m0 = (swz & 31) << 7;
  const int n0 = (swz >> 5) << 7;
  const int lrow = lane & 15, dg = lane >> 4, lq4 = dg * 4;
  const int rslot = (dg ^ ((lrow >> 1) & 3)) * 8;
  const int arow = tid >> 2;
  const int ascol = ((tid & 3) ^ ((tid >> 3) & 3)) * 8;
  const __hip_bfloat16* aS0 = A + (size_t)(m0 + arow) * 2048 + ascol;
  const __hip_bfloat16* aS1 = A + (size_t)(m0 + 64 + arow) * 2048 + ascol;
  const __hip_bfloat16* bS0 = W + (size_t)(n0 + arow) * 2048 + ascol;
  const __hip_bfloat16* bS1 = W + (size_t)(n0 + 64 + arow) * 2048 + ascol;
  float* invfp = (float*)((char*)sm + 49152);
  if (tid < 64) invfp[tid] = __expf(-(float)tid * 0.14391156831212787f);
  floatx4 acc[4][4] = {};

#define QS128(TT) do { const int bo_ = ((TT) % 3) * 8192; const int kk_ = (TT) * 32; \
    gl2lds16(aS0 + kk_, &sm[bo_ + tid * 8]);                                   \
    gl2lds16(aS1 + kk_, &sm[bo_ + 2048 + tid * 8]);                            \
    gl2lds16(bS0 + kk_, &sm[bo_ + 4096 + tid * 8]);                            \
    gl2lds16(bS1 + kk_, &sm[bo_ + 6144 + tid * 8]); } while (0)

#define QC128(BO) do {                                                         \
    bf16x8 af[4], bfr[4];                                                      \
    _Pragma("unroll")                                                          \
    for (int mt = 0; mt < 4; mt++)                                             \
      af[mt] = *(const bf16x8*)&sm[(BO) + (wr * 64 + mt * 16 + lrow) * 32 + rslot]; \
    _Pragma("unroll")                                                          \
    for (int nt = 0; nt < 4; nt++)                                             \
      bfr[nt] = *(const bf16x8*)&sm[(BO) + 4096 + (wc * 64 + nt * 16 + lrow) * 32 + rslot]; \
    __builtin_amdgcn_s_setprio(1);                                             \
    _Pragma("unroll")                                                          \
    for (int mt = 0; mt < 4; mt++)                                             \
      _Pragma("unroll")                                                        \
      for (int nt = 0; nt < 4; nt++)                                           \
        acc[mt][nt] = __builtin_amdgcn_mfma_f32_16x16x32_bf16(af[mt], bfr[nt], acc[mt][nt], 0, 0, 0); \
    __builtin_amdgcn_s_setprio(0);                                             \
  } while (0)

  QS128(0); QS128(1);
  // 0x0074 = vmcnt(4) lgkm(0); 0x0070 = vmcnt(0) lgkm(0)
  for (int t = 0; t < 63; ++t) {
    MEMFENCE; __builtin_amdgcn_s_waitcnt(0x0074); MEMFENCE;
    __builtin_amdgcn_s_barrier(); MEMFENCE;
    if (t < 62) QS128(t + 2);
    QC128((t % 3) * 8192);
  }
  MEMFENCE; __builtin_amdgcn_s_waitcnt(0x0070); MEMFENCE;
  __builtin_amdgcn_s_barrier(); MEMFENCE;
  QC128((63 % 3) * 8192);
#undef QC128
#undef QS128

  // -------- epilogue: n-tile = 1 head. RoPE (Q/K) or transpose (V) --------
  const int seg = n0 >> 11;               // 0=Q 1=K 2=V
  const int h = (n0 & 2047) >> 7;
  const int b = m0 >> 11;
  const int seq0 = m0 & 2047;
  __syncthreads();                        // K-loop LDS reads done
  if (seg < 2) {                          // Csh[row 128][136]
#pragma unroll
    for (int mt = 0; mt < 4; mt++)
#pragma unroll
      for (int nt = 0; nt < 4; nt++)
#pragma unroll
        for (int r = 0; r < 4; r++)
          sm[(wr * 64 + mt * 16 + lq4 + r) * 136 + wc * 64 + nt * 16 + lrow] =
              __float2bfloat16(acc[mt][nt][r]);
  } else {                                // CshT[col 128][136]
#pragma unroll
    for (int mt = 0; mt < 4; mt++)
#pragma unroll
      for (int nt = 0; nt < 4; nt++)
#pragma unroll
        for (int r = 0; r < 4; r++)
          sm[(wc * 64 + nt * 16 + lrow) * 136 + wr * 64 + mt * 16 + lq4 + r] =
              __float2bfloat16(acc[mt][nt][r]);
  }
  __syncthreads();
  const float qs = (seg == 0) ? 0.08838834764831845f : 1.0f;
  if (seg < 2) {
    __hip_bfloat16* Out = seg ? Kr : Qr;
#pragma unroll
    for (int it = 0; it < 4; ++it) {
      const int task = tid + it * 256;    // 1024 tasks: 128 rows x 8 col-groups
      const int row = task >> 3;
      const int g8 = (task & 7) * 8;
      const int seq = seq0 + row;
      const float pos = (float)seq;
      const bf16x8 lo8 = *(const bf16x8*)&sm[row * 136 + g8];
      const bf16x8 hi8 = *(const bf16x8*)&sm[row * 136 + g8 + 64];
      alignas(16) __hip_bfloat16 lo[8], hi[8];
#pragma unroll
      for (int k = 0; k < 8; k++) {
        float sn, cs;
        __sincosf(pos * invfp[g8 + k], &sn, &cs);
        const float a = (float)lo8[k];
        const float bb2 = (float)hi8[k];
        lo[k] = __float2bfloat16((a * cs - bb2 * sn) * qs);
        hi[k] = __float2bfloat16((bb2 * cs + a * sn) * qs);
      }
      const size_t ob = ((size_t)((b * 16 + h) * 2048 + seq)) * 128;
      *(bf16x8*)&Out[ob + g8] = *(const bf16x8*)lo;
      *(bf16x8*)&Out[ob + g8 + 64] = *(const bf16x8*)hi;
    }
  } else {
#pragma unroll
    for (int it = 0; it < 8; ++it) {
      const int task = tid + it * 256;    // 2048 tasks: 128 d x 16 seq-groups
      const int col = task >> 4;
      const int sg = (task & 15) * 8;
      const bf16x8 v8 = *(const bf16x8*)&sm[col * 136 + sg];
      *(bf16x8*)&Vt[((size_t)((b * 16 + h) * 128 + col)) * 2048 + seq0 + sg] = v8;
    }
  }
}

// ============ O-proj GEMM: 256M x 128N tile, grid 16x16 (R5, unchanged) ========
__global__ __launch_bounds__(512, 2)
void gemm_o256(const __hip_bfloat16* __restrict__ A,
               const __hip_bfloat16* __restrict__ Wo,
               float* __restrict__ C)
{
  extern __shared__ __hip_bfloat16 sm[];   // 96KB: 4 bufs x (A 8192 + B 4096)
  const int tid = threadIdx.x, lane = tid & 63, wave = tid >> 6;
  const int wr = wave >> 2, wc = wave & 3;
  const int m0 = blockIdx.x << 8, n0 = blockIdx.y << 7;
  const int lrow = lane & 15, dg = lane >> 4, lq4 = dg * 4;
  const int rslot = (dg ^ ((lrow >> 1) & 3)) * 8;
  const int arow = tid >> 2;
  const int ascol = ((tid & 3) ^ ((tid >> 3) & 3)) * 8;
  const __hip_bfloat16* aS0 = A + (size_t)(m0 + arow) * 2048 + ascol;
  const __hip_bfloat16* aS1 = A + (size_t)(m0 + 128 + arow) * 2048 + ascol;
  const __hip_bfloat16* bS0 = Wo + (size_t)(n0 + arow) * 2048 + ascol;
  floatx4 acc[8][2] = {};

#define OSTAGE(TT) do { const int bb_ = (TT) & 3; const int kk_ = (TT) * 32;   \
    gl2lds16(aS0 + kk_, &sm[bb_ * 12288 + tid * 8]);                           \
    gl2lds16(aS1 + kk_, &sm[bb_ * 12288 + 4096 + tid * 8]);                    \
    gl2lds16(bS0 + kk_, &sm[bb_ * 12288 + 8192 + tid * 8]); } while (0)

#define OKSTEP(TT, WIMM, DOSTAGE) do {                                         \
    MEMFENCE; __builtin_amdgcn_s_waitcnt(WIMM); MEMFENCE;                      \
    __builtin_amdgcn_s_barrier(); MEMFENCE;                                    \
    const int bb = (TT) & 3;                                                   \
    if (DOSTAGE) OSTAGE((TT) + 3);                                             \
    bf16x8 af[8], bfr[2];                                                      \
    _Pragma("unroll")                                                          \
    for (int mt = 0; mt < 8; mt++)                                             \
      af[mt] = *(const bf16x8*)&sm[bb * 12288 + (wr * 128 + mt * 16 + lrow) * 32 + rslot]; \
    _Pragma("unroll")                                                          \
    for (int nt = 0; nt < 2; nt++)                                             \
      bfr[nt] = *(const bf16x8*)&sm[bb * 12288 + 8192 + (wc * 32 + nt * 16 + lrow) * 32 + rslot]; \
    __builtin_amdgcn_s_setprio(1);                                             \
    _Pragma("unroll")                                                          \
    for (int mt = 0; mt < 8; mt++)                                             \
      _Pragma("unroll")                                                        \
      for (int nt = 0; nt < 2; nt++)                                           \
        acc[mt][nt] = __builtin_amdgcn_mfma_f32_16x16x32_bf16(af[mt], bfr[nt], acc[mt][nt], 0, 0, 0); \
    __builtin_amdgcn_s_setprio(0);                                             \
  } while (0)

  OSTAGE(0); OSTAGE(1); OSTAGE(2);   // 9 VMEM in flight
  // 0x0076=vmcnt(6)lgkm(0)  0x0073=vmcnt(3)  0x0070=vmcnt(0)
  for (int t = 0; t < 61; ++t) OKSTEP(t, 0x0076, true);
  OKSTEP(61, 0x0076, false);
  OKSTEP(62, 0x0073, false);
  OKSTEP(63, 0x0070, false);
#undef OKSTEP
#undef OSTAGE

#pragma unroll
  for (int mt = 0; mt < 8; mt++)
#pragma unroll
    for (int nt = 0; nt < 2; nt++)
#pragma unroll
      for (int r = 0; r < 4; r++)
        C[(size_t)(m0 + wr * 128 + mt * 16 + lq4 + r) * 2048 +
          (n0 + wc * 32 + nt * 16 + lrow)] = acc[mt][nt][r];
}

// ---------------- sliding-window flash attention (unchanged) ----------------
#define KSTR 136
#define VSTR 72
__global__ __launch_bounds__(512, 4)
void attn_swa(const __hip_bfloat16* __restrict__ Qr, const __hip_bfloat16* __restrict__ Kr,
              const __hip_bfloat16* __restrict__ Vt, __hip_bfloat16* __restrict__ Out)
{
  __shared__ __hip_bfloat16 Ks[64 * KSTR];
  __shared__ __hip_bfloat16 Vs[128 * VSTR];
  __shared__ __hip_bfloat16 Pb[8][16 * VSTR];
  const int qt = blockIdx.x, bh = blockIdx.y;
  const int tid = threadIdx.x, lane = tid & 63, wave = tid >> 6;
  const int lrow = lane & 15, lk = (lane >> 4) * 8, lq4 = (lane >> 4) * 4;
  const int i0 = qt * 128;
  const float NEG_INF = -__builtin_inff();
  const __hip_bfloat16* Qh = Qr + (size_t)bh * 2048 * 128;
  const __hip_bfloat16* Kh = Kr + (size_t)bh * 2048 * 128;
  const __hip_bfloat16* Vh = Vt + (size_t)bh * 128 * 2048;

  const int ck0 = tid, ck1 = tid + 512;
  const int kr0 = ck0 >> 4, kg0 = (ck0 & 15) * 8;
  const int kr1 = ck1 >> 4, kg1 = (ck1 & 15) * 8;
  const int cv0 = tid, cv1 = tid + 512;
  const int vd0 = cv0 >> 3, vc0 = (cv0 & 7) * 8;
  const int vd1 = cv1 >> 3, vc1 = (cv1 & 7) * 8;

  const int iw = i0 + wave * 16 + lrow;
  bf16x8 qf[4];
#pragma unroll
  for (int ks = 0; ks < 4; ks++)
    qf[ks] = *(const bf16x8*)&Qh[(size_t)iw * 128 + ks * 32 + lk];

  floatx4 accO[8] = {};
  float m_i = NEG_INF, l_i = 0.f;
  const int imin = i0 + wave * 16;
  const int lo = i0 - 511;
  const int jt_lo = (lo > 0 ? lo : 0) >> 6;
  const int jt_hi = (i0 + 127) >> 6;

  int j0n = jt_lo * 64;
  int4 rk0 = *(const int4*)&Kh[(size_t)(j0n + kr0) * 128 + kg0];
  int4 rk1 = *(const int4*)&Kh[(size_t)(j0n + kr1) * 128 + kg1];
  int4 rv0 = *(const int4*)&Vh[(size_t)vd0 * 2048 + j0n + vc0];
  int4 rv1 = *(const int4*)&Vh[(size_t)vd1 * 2048 + j0n + vc1];

  for (int jt = jt_lo; jt <= jt_hi; jt++) {
    const int j0 = jt * 64;
    __syncthreads();
    *(int4*)&Ks[kr0 * KSTR + kg0] = rk0;
    *(int4*)&Ks[kr1 * KSTR + kg1] = rk1;
    *(int4*)&Vs[vd0 * VSTR + vc0] = rv0;
    *(int4*)&Vs[vd1 * VSTR + vc1] = rv1;
    if (jt < jt_hi) {
      const int jn = j0 + 64;
      rk0 = *(const int4*)&Kh[(size_t)(jn + kr0) * 128 + kg0];
      rk1 = *(const int4*)&Kh[(size_t)(jn + kr1) * 128 + kg1];
      rv0 = *(const int4*)&Vh[(size_t)vd0 * 2048 + jn + vc0];
      rv1 = *(const int4*)&Vh[(size_t)vd1 * 2048 + jn + vc1];
    }
    asm volatile("" ::: "memory");
    __builtin_amdgcn_s_waitcnt(0xC07F);
    __builtin_amdgcn_s_barrier();
    asm volatile("" ::: "memory");

    floatx4 s[4] = {};
#pragma unroll
    for (int nt = 0; nt < 4; nt++) {
      const int krow = (nt * 16 + lrow) * KSTR;
#pragma unroll
      for (int ks = 0; ks < 4; ks++) {
        const bf16x8 kf = *(const bf16x8*)&Ks[krow + ks * 32 + lk];
        s[nt] = __builtin_amdgcn_mfma_f32_16x16x32_bf16(kf, qf[ks], s[nt], 0, 0, 0);
      }
    }
    const bool full = (j0 + 63 <= imin) && (j0 >= imin + 15 - 511);
    float rmax = NEG_INF;
    if (full) {
#pragma unroll
      for (int nt = 0; nt < 4; nt++)
#pragma unroll
        for (int r = 0; r < 4; r++) rmax = fmaxf(rmax, s[nt][r]);
    } else {
#pragma unroll
      for (int nt = 0; nt < 4; nt++) {
#pragma unroll
        for (int r = 0; r < 4; r++) {
          const int j = j0 + nt * 16 + lq4 + r;
          const float sv = ((j <= iw) && (j > iw - 512)) ? s[nt][r] : NEG_INF;
          s[nt][r] = sv;
          rmax = fmaxf(rmax, sv);
        }
      }
    }
    rmax = fmaxf(rmax, __shfl_xor(rmax, 16));
    rmax = fmaxf(rmax, __shfl_xor(rmax, 32));
    const float mnew = fmaxf(m_i, rmax);
    const float alpha = __expf(fminf(m_i - mnew, 0.f));
    m_i = mnew;
    float rs = 0.f;
    if (full) {
#pragma unroll
      for (int nt = 0; nt < 4; nt++)
#pragma unroll
        for (int r = 0; r < 4; r++) {
          const float p = __expf(s[nt][r] - mnew);
          s[nt][r] = p;
          rs += p;
        }
    } else {
#pragma unroll
      for (int nt = 0; nt < 4; nt++)
#pragma unroll
        for (int r = 0; r < 4; r++) {
          const float sv = s[nt][r];
          const float p = (sv == NEG_INF) ? 0.f : __expf(sv - mnew);
          s[nt][r] = p;
          rs += p;
        }
    }
    rs += __shfl_xor(rs, 16);
    rs += __shfl_xor(rs, 32);
    l_i = l_i * alpha + rs;
#pragma unroll
    for (int dt = 0; dt < 8; dt++) accO[dt] *= alpha;
#pragma unroll
    for (int nt = 0; nt < 4; nt++) {
      alignas(8) __hip_bfloat16 p4[4];
#pragma unroll
      for (int r = 0; r < 4; r++) p4[r] = __float2bfloat16(s[nt][r]);
      *(uint64_t*)&Pb[wave][lrow * VSTR + nt * 16 + lq4] = *(const uint64_t*)p4;
    }
    bf16x8 pf[2];
#pragma unroll
    for (int jf = 0; jf < 2; jf++)
      pf[jf] = *(const bf16x8*)&Pb[wave][lrow * VSTR + jf * 32 + lk];
#pragma unroll
    for (int dt = 0; dt < 8; dt++) {
      const int vrow = (dt * 16 + lrow) * VSTR;
#pragma unroll
      for (int jf = 0; jf < 2; jf++) {
        const bf16x8 vf = *(const bf16x8*)&Vs[vrow + jf * 32 + lk];
        accO[dt] = __builtin_amdgcn_mfma_f32_16x16x32_bf16(vf, pf[jf], accO[dt], 0, 0, 0);
      }
    }
  }
  const int b = bh >> 4, h = bh & 15;
  const float inv_l = 1.0f / l_i;
  const size_t rowb = ((size_t)(b * 2048 + iw)) * 2048 + h * 128;
#pragma unroll
  for (int dt = 0; dt < 8; dt++) {
    alignas(8) __hip_bfloat16 o4[4];
#pragma unroll
    for (int r = 0; r < 4; r++) o4[r] = __float2bfloat16(accO[dt][r] * inv_l);
    *(uint64_t*)&Out[rowb + dt * 16 + lq4] = *(const uint64_t*)o4;
  }
}

// ---------------- launch ----------------
extern "C" void kernel_launch(void* const* d_in, const int* in_sizes, int n_in,
                              void* d_out, int out_size, void* d_ws, size_t ws_size,
                              hipStream_t stream)
{
  const float* x = (const float*)d_in[0];      // [2,2048,2048]
  const float* w_qkv = (const float*)d_in[1];  // [6144,2048]
  const float* w_o = (const float*)d_in[2];    // [2048,2048]
  float* y = (float*)d_out;                    // [2,2048,2048] fp32
  char* ws = (char*)d_ws;

  const size_t SZ_X = 16777216;     // 4096*2048*2 B
  const size_t SZ_WQKV = 25165824;  // 6144*2048*2 B
  const size_t SZ_Q = 16777216;     // 32*2048*128*2 B

  __hip_bfloat16* xb = (__hip_bfloat16*)(ws);            // x bf16; later attn out
  __hip_bfloat16* wqkvb = (__hip_bfloat16*)(ws + SZ_X);  // w_qkv bf16; later w_o bf16
  __hip_bfloat16* Qr = (__hip_bfloat16*)(ws + SZ_X + SZ_WQKV);
  __hip_bfloat16* Kr = (__hip_bfloat16*)(ws + SZ_X + SZ_WQKV + SZ_Q);
  __hip_bfloat16* Vt = (__hip_bfloat16*)(ws + SZ_X + SZ_WQKV + 2 * SZ_Q);

  static bool s_attr_done = false;
  if (!s_attr_done) {
    hipFuncSetAttribute((const void*)gemm_o256,
                        hipFuncAttributeMaxDynamicSharedMemorySize, 98304);
    s_attr_done = true;
  }

  // x + w_qkv converted in one launch (outputs are contiguous in ws)
  cvt2_kernel<<<dim3(20480), dim3(256), 0, stream>>>(x, w_qkv, xb, 8388608, 20971520);
  gemm_qkv128<<<dim3(32, 48), dim3(256), 49408, stream>>>(xb, wqkvb, Qr, Kr, Vt);
  attn_swa<<<dim3(16, 32), dim3(512), 0, stream>>>(Qr, Kr, Vt, xb /*attn_out*/);
  cvt_kernel<<<dim3(4096), dim3(256), 0, stream>>>(w_o, wqkvb, 4194304);
  gemm_o256<<<dim3(16, 16), dim3(512), 98304, stream>>>(xb, wqkvb, y);
}

// Round 7
// 353.229 us; speedup vs baseline: 1.0131x; 1.0131x over previous
//
#include <hip/hip_runtime.h>
#include <hip/hip_bf16.h>
#include <cstdint>

typedef __bf16 bf16x8 __attribute__((ext_vector_type(8)));
typedef float floatx4 __attribute__((ext_vector_type(4)));

__device__ __forceinline__ void gl2lds16(const void* g, void* l) {
  __builtin_amdgcn_global_load_lds(
      (const __attribute__((address_space(1))) unsigned int*)g,
      (__attribute__((address_space(3))) unsigned int*)(uintptr_t)l,
      16, 0, 0);
}

// ---------------- fp32 -> bf16 convert ----------------
__global__ __launch_bounds__(256)
void cvt_kernel(const float* __restrict__ in, __hip_bfloat16* __restrict__ out, int n) {
  int i = (blockIdx.x * 256 + threadIdx.x) * 4;
  if (i >= n) return;
  const float4 v = *(const float4*)(in + i);
  out[i + 0] = __float2bfloat16(v.x);
  out[i + 1] = __float2bfloat16(v.y);
  out[i + 2] = __float2bfloat16(v.z);
  out[i + 3] = __float2bfloat16(v.w);
}

// fused cvt of x (n0 elems) and w_qkv into one contiguous bf16 output
__global__ __launch_bounds__(256)
void cvt2_kernel(const float* __restrict__ in0, const float* __restrict__ in1,
                 __hip_bfloat16* __restrict__ out, int n0, int ntot) {
  int i = (blockIdx.x * 256 + threadIdx.x) * 4;
  if (i >= ntot) return;
  const float4 v = (i < n0) ? *(const float4*)(in0 + i)
                            : *(const float4*)(in1 + (i - n0));
  out[i + 0] = __float2bfloat16(v.x);
  out[i + 1] = __float2bfloat16(v.y);
  out[i + 2] = __float2bfloat16(v.z);
  out[i + 3] = __float2bfloat16(v.w);
}

#define MEMFENCE asm volatile("" ::: "memory")

// ================= 256x256 QKV GEMM (R2/R5-validated single-barrier K-loop) ====
__global__ __launch_bounds__(512, 2)
void gemm_qkv256(const __hip_bfloat16* __restrict__ A,
                 const __hip_bfloat16* __restrict__ W,
                 __hip_bfloat16* __restrict__ Qr,
                 __hip_bfloat16* __restrict__ Kr,
                 __hip_bfloat16* __restrict__ Vt)
{
  extern __shared__ __hip_bfloat16 sm[];   // 128KB: 4 bufs x (A 8192 + B 8192)
  const int tid = threadIdx.x, lane = tid & 63, wave = tid >> 6;
  const int wr = wave >> 2, wc = wave & 3;
  const int m0 = blockIdx.x << 8, n0 = blockIdx.y << 8;
  const int lrow = lane & 15, dg = lane >> 4, lq4 = dg * 4;
  const int rslot = (dg ^ ((lrow >> 1) & 3)) * 8;
  const int arow = tid >> 2;
  const int ascol = ((tid & 3) ^ ((tid >> 3) & 3)) * 8;
  const __hip_bfloat16* aS0 = A + (size_t)(m0 + arow) * 2048 + ascol;
  const __hip_bfloat16* aS1 = A + (size_t)(m0 + 128 + arow) * 2048 + ascol;
  const __hip_bfloat16* bS0 = W + (size_t)(n0 + arow) * 2048 + ascol;
  const __hip_bfloat16* bS1 = W + (size_t)(n0 + 128 + arow) * 2048 + ascol;
  floatx4 acc[8][4] = {};

#define QSTAGE(TT) do { const int bb_ = (TT) & 3; const int kk_ = (TT) * 32;   \
    gl2lds16(aS0 + kk_, &sm[bb_ * 16384 + tid * 8]);                           \
    gl2lds16(aS1 + kk_, &sm[bb_ * 16384 + 4096 + tid * 8]);                    \
    gl2lds16(bS0 + kk_, &sm[bb_ * 16384 + 8192 + tid * 8]);                    \
    gl2lds16(bS1 + kk_, &sm[bb_ * 16384 + 12288 + tid * 8]); } while (0)

#define QKSTEP(TT, WIMM, DOSTAGE) do {                                         \
    MEMFENCE; __builtin_amdgcn_s_waitcnt(WIMM); MEMFENCE;                      \
    __builtin_amdgcn_s_barrier(); MEMFENCE;                                    \
    const int bb = (TT) & 3;                                                   \
    if (DOSTAGE) QSTAGE((TT) + 3);                                             \
    bf16x8 af[8], bfr[4];                                                      \
    _Pragma("unroll")                                                          \
    for (int mt = 0; mt < 8; mt++)                                             \
      af[mt] = *(const bf16x8*)&sm[bb * 16384 + (wr * 128 + mt * 16 + lrow) * 32 + rslot]; \
    _Pragma("unroll")                                                          \
    for (int nt = 0; nt < 4; nt++)                                             \
      bfr[nt] = *(const bf16x8*)&sm[bb * 16384 + 8192 + (wc * 64 + nt * 16 + lrow) * 32 + rslot]; \
    __builtin_amdgcn_s_setprio(1);                                             \
    _Pragma("unroll")                                                          \
    for (int mt = 0; mt < 8; mt++)                                             \
      _Pragma("unroll")                                                        \
      for (int nt = 0; nt < 4; nt++)                                           \
        acc[mt][nt] = __builtin_amdgcn_mfma_f32_16x16x32_bf16(af[mt], bfr[nt], acc[mt][nt], 0, 0, 0); \
    __builtin_amdgcn_s_setprio(0);                                             \
  } while (0)

  QSTAGE(0); QSTAGE(1); QSTAGE(2);   // 12 VMEM in flight
  // 0x0078=vmcnt(8)lgkm(0)  0x0074=vmcnt(4)  0x0070=vmcnt(0)
  for (int t = 0; t < 61; ++t) QKSTEP(t, 0x0078, true);
  QKSTEP(61, 0x0078, false);
  QKSTEP(62, 0x0074, false);
  QKSTEP(63, 0x0070, false);
#undef QKSTEP
#undef QSTAGE

  // -------- epilogue: RoPE (Q/K) or transpose (V), via LDS restage --------
  const int seg = n0 >> 11;               // 0=Q 1=K 2=V
  const int h0 = (n0 & 2047) >> 7;
  const int b = m0 >> 11;
  const int seq0 = m0 & 2047;
  float* invfp = (float*)((char*)sm + 122880);

  __syncthreads();
  if (seg < 2 && tid < 64) invfp[tid] = __expf(-(float)tid * 0.14391156831212787f);

  const float qs = (seg == 0) ? 0.08838834764831845f : 1.0f;
  for (int p = 0; p < 2; ++p) {
    if (p) __syncthreads();
    if (wr == p) {
      if (seg < 2) {                      // Csh[row(128)][264]
#pragma unroll
        for (int mt = 0; mt < 8; mt++)
#pragma unroll
          for (int nt = 0; nt < 4; nt++)
#pragma unroll
            for (int r = 0; r < 4; r++)
              sm[(mt * 16 + lq4 + r) * 264 + wc * 64 + nt * 16 + lrow] =
                  __float2bfloat16(acc[mt][nt][r]);
      } else {                            // CshT[col(256)][136]
#pragma unroll
        for (int mt = 0; mt < 8; mt++)
#pragma unroll
          for (int nt = 0; nt < 4; nt++)
#pragma unroll
            for (int r = 0; r < 4; r++)
              sm[(wc * 64 + nt * 16 + lrow) * 136 + mt * 16 + lq4 + r] =
                  __float2bfloat16(acc[mt][nt][r]);
      }
    }
    __syncthreads();
    if (seg < 2) {
      __hip_bfloat16* Out = seg ? Kr : Qr;
#pragma unroll
      for (int it = 0; it < 4; ++it) {
        const int task = tid + it * 512;
        const int row = task >> 4;
        const int hh = (task >> 3) & 1;
        const int g8 = (task & 7) * 8;
        const int seq = seq0 + p * 128 + row;
        const float pos = (float)seq;
        const bf16x8 lo8 = *(const bf16x8*)&sm[row * 264 + hh * 128 + g8];
        const bf16x8 hi8 = *(const bf16x8*)&sm[row * 264 + hh * 128 + g8 + 64];
        alignas(16) __hip_bfloat16 lo[8], hi[8];
#pragma unroll
        for (int k = 0; k < 8; k++) {
          float sn, cs;
          __sincosf(pos * invfp[g8 + k], &sn, &cs);
          const float a = (float)lo8[k];
          const float bb2 = (float)hi8[k];
          lo[k] = __float2bfloat16((a * cs - bb2 * sn) * qs);
          hi[k] = __float2bfloat16((bb2 * cs + a * sn) * qs);
        }
        const size_t ob = ((size_t)((b * 16 + h0 + hh) * 2048 + seq)) * 128;
        *(bf16x8*)&Out[ob + g8] = *(const bf16x8*)lo;
        *(bf16x8*)&Out[ob + g8 + 64] = *(const bf16x8*)hi;
      }
    } else {
#pragma unroll
      for (int it = 0; it < 8; ++it) {
        const int task = tid + it * 512;
        const int col = task >> 4;
        const int sg = (task & 15) * 8;
        const bf16x8 v8 = *(const bf16x8*)&sm[col * 136 + sg];
        const int hh = col >> 7, d = col & 127;
        *(bf16x8*)&Vt[((size_t)((b * 16 + h0 + hh) * 128 + d)) * 2048 + seq0 + p * 128 + sg] = v8;
      }
    }
  }
}

// ============ O-proj GEMM: 256M x 128N tile, grid 16x16 (R5, unchanged) ========
__global__ __launch_bounds__(512, 2)
void gemm_o256(const __hip_bfloat16* __restrict__ A,
               const __hip_bfloat16* __restrict__ Wo,
               float* __restrict__ C)
{
  extern __shared__ __hip_bfloat16 sm[];   // 96KB: 4 bufs x (A 8192 + B 4096)
  const int tid = threadIdx.x, lane = tid & 63, wave = tid >> 6;
  const int wr = wave >> 2, wc = wave & 3;
  const int m0 = blockIdx.x << 8, n0 = blockIdx.y << 7;
  const int lrow = lane & 15, dg = lane >> 4, lq4 = dg * 4;
  const int rslot = (dg ^ ((lrow >> 1) & 3)) * 8;
  const int arow = tid >> 2;
  const int ascol = ((tid & 3) ^ ((tid >> 3) & 3)) * 8;
  const __hip_bfloat16* aS0 = A + (size_t)(m0 + arow) * 2048 + ascol;
  const __hip_bfloat16* aS1 = A + (size_t)(m0 + 128 + arow) * 2048 + ascol;
  const __hip_bfloat16* bS0 = Wo + (size_t)(n0 + arow) * 2048 + ascol;
  floatx4 acc[8][2] = {};

#define OSTAGE(TT) do { const int bb_ = (TT) & 3; const int kk_ = (TT) * 32;   \
    gl2lds16(aS0 + kk_, &sm[bb_ * 12288 + tid * 8]);                           \
    gl2lds16(aS1 + kk_, &sm[bb_ * 12288 + 4096 + tid * 8]);                    \
    gl2lds16(bS0 + kk_, &sm[bb_ * 12288 + 8192 + tid * 8]); } while (0)

#define OKSTEP(TT, WIMM, DOSTAGE) do {                                         \
    MEMFENCE; __builtin_amdgcn_s_waitcnt(WIMM); MEMFENCE;                      \
    __builtin_amdgcn_s_barrier(); MEMFENCE;                                    \
    const int bb = (TT) & 3;                                                   \
    if (DOSTAGE) OSTAGE((TT) + 3);                                             \
    bf16x8 af[8], bfr[2];                                                      \
    _Pragma("unroll")                                                          \
    for (int mt = 0; mt < 8; mt++)                                             \
      af[mt] = *(const bf16x8*)&sm[bb * 12288 + (wr * 128 + mt * 16 + lrow) * 32 + rslot]; \
    _Pragma("unroll")                                                          \
    for (int nt = 0; nt < 2; nt++)                                             \
      bfr[nt] = *(const bf16x8*)&sm[bb * 12288 + 8192 + (wc * 32 + nt * 16 + lrow) * 32 + rslot]; \
    __builtin_amdgcn_s_setprio(1);                                             \
    _Pragma("unroll")                                                          \
    for (int mt = 0; mt < 8; mt++)                                             \
      _Pragma("unroll")                                                        \
      for (int nt = 0; nt < 2; nt++)                                           \
        acc[mt][nt] = __builtin_amdgcn_mfma_f32_16x16x32_bf16(af[mt], bfr[nt], acc[mt][nt], 0, 0, 0); \
    __builtin_amdgcn_s_setprio(0);                                             \
  } while (0)

  OSTAGE(0); OSTAGE(1); OSTAGE(2);   // 9 VMEM in flight
  // 0x0076=vmcnt(6)lgkm(0)  0x0073=vmcnt(3)  0x0070=vmcnt(0)
  for (int t = 0; t < 61; ++t) OKSTEP(t, 0x0076, true);
  OKSTEP(61, 0x0076, false);
  OKSTEP(62, 0x0073, false);
  OKSTEP(63, 0x0070, false);
#undef OKSTEP
#undef OSTAGE

#pragma unroll
  for (int mt = 0; mt < 8; mt++)
#pragma unroll
    for (int nt = 0; nt < 2; nt++)
#pragma unroll
      for (int r = 0; r < 4; r++)
        C[(size_t)(m0 + wr * 128 + mt * 16 + lq4 + r) * 2048 +
          (n0 + wc * 32 + nt * 16 + lrow)] = acc[mt][nt][r];
}

// ====== sliding-window flash attention: XCD-local heads + depth-2 prefetch ======
// Grid (bh=x 32, qt=y 16): dispatch idx = bh + 32*qt, XCD = idx%8 -> XCD i
// serves only heads bh === i (mod 8): 4 heads x 1MB K/V = 4MB = L2-resident.
// Loop-top barrier is RAW (no vmcnt drain): prev-iter LDS reads are lgkm-retired
// before each wave's MFMAs, hence before the barrier. Current tile's reg
// readiness is enforced by the compiler's counted vmcnt at the LDS-write.
// Depth-2 prefetch via two named reg sets (A/B), ping-pong unrolled (jt += 2).
#define KSTR 136
#define VSTR 72
__global__ __launch_bounds__(512, 4)
void attn_swa(const __hip_bfloat16* __restrict__ Qr, const __hip_bfloat16* __restrict__ Kr,
              const __hip_bfloat16* __restrict__ Vt, __hip_bfloat16* __restrict__ Out)
{
  __shared__ __hip_bfloat16 Ks[64 * KSTR];
  __shared__ __hip_bfloat16 Vs[128 * VSTR];
  __shared__ __hip_bfloat16 Pb[8][16 * VSTR];
  const int bh = blockIdx.x, qt = blockIdx.y;   // swapped: XCD locality on heads
  const int tid = threadIdx.x, lane = tid & 63, wave = tid >> 6;
  const int lrow = lane & 15, lk = (lane >> 4) * 8, lq4 = (lane >> 4) * 4;
  const int i0 = qt * 128;
  const float NEG_INF = -__builtin_inff();
  const __hip_bfloat16* Qh = Qr + (size_t)bh * 2048 * 128;
  const __hip_bfloat16* Kh = Kr + (size_t)bh * 2048 * 128;
  const __hip_bfloat16* Vh = Vt + (size_t)bh * 128 * 2048;

  const int ck0 = tid, ck1 = tid + 512;
  const int kr0 = ck0 >> 4, kg0 = (ck0 & 15) * 8;
  const int kr1 = ck1 >> 4, kg1 = (ck1 & 15) * 8;
  const int cv0 = tid, cv1 = tid + 512;
  const int vd0 = cv0 >> 3, vc0 = (cv0 & 7) * 8;
  const int vd1 = cv1 >> 3, vc1 = (cv1 & 7) * 8;

  const int iw = i0 + wave * 16 + lrow;
  bf16x8 qf[4];
#pragma unroll
  for (int ks = 0; ks < 4; ks++)
    qf[ks] = *(const bf16x8*)&Qh[(size_t)iw * 128 + ks * 32 + lk];

  floatx4 accO[8] = {};
  float m_i = NEG_INF, l_i = 0.f;
  const int imin = i0 + wave * 16;
  const int lo = i0 - 511;
  const int jt_lo = (lo > 0 ? lo : 0) >> 6;
  const int jt_hi = (i0 + 127) >> 6;            // >= jt_lo + 1 always

  // depth-2 prologue: tiles jt_lo (A) and jt_lo+1 (B)
  const int jA0 = jt_lo * 64, jB0 = jA0 + 64;
  int4 rk0A = *(const int4*)&Kh[(size_t)(jA0 + kr0) * 128 + kg0];
  int4 rk1A = *(const int4*)&Kh[(size_t)(jA0 + kr1) * 128 + kg1];
  int4 rv0A = *(const int4*)&Vh[(size_t)vd0 * 2048 + jA0 + vc0];
  int4 rv1A = *(const int4*)&Vh[(size_t)vd1 * 2048 + jA0 + vc1];
  int4 rk0B = *(const int4*)&Kh[(size_t)(jB0 + kr0) * 128 + kg0];
  int4 rk1B = *(const int4*)&Kh[(size_t)(jB0 + kr1) * 128 + kg1];
  int4 rv0B = *(const int4*)&Vh[(size_t)vd0 * 2048 + jB0 + vc0];
  int4 rv1B = *(const int4*)&Vh[(size_t)vd1 * 2048 + jB0 + vc1];

#define ATT_BODY(JT, RK0, RK1, RV0, RV1) do {                                  \
    const int j0 = (JT) * 64;                                                  \
    MEMFENCE; __builtin_amdgcn_s_barrier(); MEMFENCE;                          \
    *(int4*)&Ks[kr0 * KSTR + kg0] = RK0;                                       \
    *(int4*)&Ks[kr1 * KSTR + kg1] = RK1;                                       \
    *(int4*)&Vs[vd0 * VSTR + vc0] = RV0;                                       \
    *(int4*)&Vs[vd1 * VSTR + vc1] = RV1;                                       \
    if ((JT) + 2 <= jt_hi) {                                                   \
      const int jn = j0 + 128;                                                 \
      RK0 = *(const int4*)&Kh[(size_t)(jn + kr0) * 128 + kg0];                 \
      RK1 = *(const int4*)&Kh[(size_t)(jn + kr1) * 128 + kg1];                 \
      RV0 = *(const int4*)&Vh[(size_t)vd0 * 2048 + jn + vc0];                  \
      RV1 = *(const int4*)&Vh[(size_t)vd1 * 2048 + jn + vc1];                  \
    }                                                                          \
    MEMFENCE; __builtin_amdgcn_s_waitcnt(0xC07F);                              \
    __builtin_amdgcn_s_barrier(); MEMFENCE;                                    \
    floatx4 s[4] = {};                                                         \
    _Pragma("unroll")                                                          \
    for (int nt = 0; nt < 4; nt++) {                                           \
      const int krow = (nt * 16 + lrow) * KSTR;                                \
      _Pragma("unroll")                                                        \
      for (int ks = 0; ks < 4; ks++) {                                         \
        const bf16x8 kf = *(const bf16x8*)&Ks[krow + ks * 32 + lk];            \
        s[nt] = __builtin_amdgcn_mfma_f32_16x16x32_bf16(kf, qf[ks], s[nt], 0, 0, 0); \
      }                                                                        \
    }                                                                          \
    const bool full = (j0 + 63 <= imin) && (j0 >= imin + 15 - 511);            \
    float rmax = NEG_INF;                                                      \
    if (full) {                                                                \
      _Pragma("unroll")                                                        \
      for (int nt = 0; nt < 4; nt++)                                           \
        _Pragma("unroll")                                                      \
        for (int r = 0; r < 4; r++) rmax = fmaxf(rmax, s[nt][r]);              \
    } else {                                                                   \
      _Pragma("unroll")                                                        \
      for (int nt = 0; nt < 4; nt++) {                                         \
        _Pragma("unroll")                                                      \
        for (int r = 0; r < 4; r++) {                                          \
          const int j = j0 + nt * 16 + lq4 + r;                                \
          const float sv = ((j <= iw) && (j > iw - 512)) ? s[nt][r] : NEG_INF; \
          s[nt][r] = sv;                                                       \
          rmax = fmaxf(rmax, sv);                                              \
        }                                                                      \
      }                                                                        \
    }                                                                          \
    rmax = fmaxf(rmax, __shfl_xor(rmax, 16));                                  \
    rmax = fmaxf(rmax, __shfl_xor(rmax, 32));                                  \
    const float mnew = fmaxf(m_i, rmax);                                       \
    const float alpha = __expf(fminf(m_i - mnew, 0.f));                        \
    m_i = mnew;                                                                \
    float rs = 0.f;                                                            \
    if (full) {                                                                \
      _Pragma("unroll")                                                        \
      for (int nt = 0; nt < 4; nt++)                                           \
        _Pragma("unroll")                                                      \
        for (int r = 0; r < 4; r++) {                                          \
          const float p = __expf(s[nt][r] - mnew);                             \
          s[nt][r] = p;                                                        \
          rs += p;                                                             \
        }                                                                      \
    } else {                                                                   \
      _Pragma("unroll")                                                        \
      for (int nt = 0; nt < 4; nt++)                                           \
        _Pragma("unroll")                                                      \
        for (int r = 0; r < 4; r++) {                                          \
          const float sv = s[nt][r];                                           \
          const float p = (sv == NEG_INF) ? 0.f : __expf(sv - mnew);           \
          s[nt][r] = p;                                                        \
          rs += p;                                                             \
        }                                                                      \
    }                                                                          \
    rs += __shfl_xor(rs, 16);                                                  \
    rs += __shfl_xor(rs, 32);                                                  \
    l_i = l_i * alpha + rs;                                                    \
    _Pragma("unroll")                                                          \
    for (int dt = 0; dt < 8; dt++) accO[dt] *= alpha;                          \
    _Pragma("unroll")                                                          \
    for (int nt = 0; nt < 4; nt++) {                                           \
      alignas(8) __hip_bfloat16 p4[4];                                         \
      _Pragma("unroll")                                                        \
      for (int r = 0; r < 4; r++) p4[r] = __float2bfloat16(s[nt][r]);          \
      *(uint64_t*)&Pb[wave][lrow * VSTR + nt * 16 + lq4] = *(const uint64_t*)p4; \
    }                                                                          \
    bf16x8 pf[2];                                                              \
    _Pragma("unroll")                                                          \
    for (int jf = 0; jf < 2; jf++)                                             \
      pf[jf] = *(const bf16x8*)&Pb[wave][lrow * VSTR + jf * 32 + lk];          \
    _Pragma("unroll")                                                          \
    for (int dt = 0; dt < 8; dt++) {                                           \
      const int vrow = (dt * 16 + lrow) * VSTR;                                \
      _Pragma("unroll")                                                        \
      for (int jf = 0; jf < 2; jf++) {                                         \
        const bf16x8 vf = *(const bf16x8*)&Vs[vrow + jf * 32 + lk];            \
        accO[dt] = __builtin_amdgcn_mfma_f32_16x16x32_bf16(vf, pf[jf], accO[dt], 0, 0, 0); \
      }                                                                        \
    }                                                                          \
  } while (0)

  for (int jt = jt_lo; jt <= jt_hi; jt += 2) {
    ATT_BODY(jt, rk0A, rk1A, rv0A, rv1A);
    if (jt + 1 <= jt_hi) ATT_BODY(jt + 1, rk0B, rk1B, rv0B, rv1B);
  }
#undef ATT_BODY

  const int b = bh >> 4, h = bh & 15;
  const float inv_l = 1.0f / l_i;
  const size_t rowb = ((size_t)(b * 2048 + iw)) * 2048 + h * 128;
#pragma unroll
  for (int dt = 0; dt < 8; dt++) {
    alignas(8) __hip_bfloat16 o4[4];
#pragma unroll
    for (int r = 0; r < 4; r++) o4[r] = __float2bfloat16(accO[dt][r] * inv_l);
    *(uint64_t*)&Out[rowb + dt * 16 + lq4] = *(const uint64_t*)o4;
  }
}

// ---------------- launch ----------------
extern "C" void kernel_launch(void* const* d_in, const int* in_sizes, int n_in,
                              void* d_out, int out_size, void* d_ws, size_t ws_size,
                              hipStream_t stream)
{
  const float* x = (const float*)d_in[0];      // [2,2048,2048]
  const float* w_qkv = (const float*)d_in[1];  // [6144,2048]
  const float* w_o = (const float*)d_in[2];    // [2048,2048]
  float* y = (float*)d_out;                    // [2,2048,2048] fp32
  char* ws = (char*)d_ws;

  const size_t SZ_X = 16777216;     // 4096*2048*2 B
  const size_t SZ_WQKV = 25165824;  // 6144*2048*2 B
  const size_t SZ_Q = 16777216;     // 32*2048*128*2 B

  __hip_bfloat16* xb = (__hip_bfloat16*)(ws);            // x bf16; later attn out
  __hip_bfloat16* wqkvb = (__hip_bfloat16*)(ws + SZ_X);  // w_qkv bf16; later w_o bf16
  __hip_bfloat16* Qr = (__hip_bfloat16*)(ws + SZ_X + SZ_WQKV);
  __hip_bfloat16* Kr = (__hip_bfloat16*)(ws + SZ_X + SZ_WQKV + SZ_Q);
  __hip_bfloat16* Vt = (__hip_bfloat16*)(ws + SZ_X + SZ_WQKV + 2 * SZ_Q);

  static bool s_attr_done = false;
  if (!s_attr_done) {
    hipFuncSetAttribute((const void*)gemm_qkv256,
                        hipFuncAttributeMaxDynamicSharedMemorySize, 131072);
    hipFuncSetAttribute((const void*)gemm_o256,
                        hipFuncAttributeMaxDynamicSharedMemorySize, 98304);
    s_attr_done = true;
  }

  // x + w_qkv converted in one launch (outputs are contiguous in ws)
  cvt2_kernel<<<dim3(20480), dim3(256), 0, stream>>>(x, w_qkv, xb, 8388608, 20971520);
  gemm_qkv256<<<dim3(16, 24), dim3(512), 131072, stream>>>(xb, wqkvb, Qr, Kr, Vt);
  attn_swa<<<dim3(32, 16), dim3(512), 0, stream>>>(Qr, Kr, Vt, xb /*attn_out*/);
  cvt_kernel<<<dim3(4096), dim3(256), 0, stream>>>(w_o, wqkvb, 4194304);
  gemm_o256<<<dim3(16, 16), dim3(512), 98304, stream>>>(xb, wqkvb, y);
}

// Round 8
// 340.459 us; speedup vs baseline: 1.0511x; 1.0375x over previous
//
#include <hip/hip_runtime.h>
#include <hip/hip_bf16.h>
#include <cstdint>

typedef __bf16 bf16x8 __attribute__((ext_vector_type(8)));
typedef float floatx4 __attribute__((ext_vector_type(4)));

__device__ __forceinline__ void gl2lds16(const void* g, void* l) {
  __builtin_amdgcn_global_load_lds(
      (const __attribute__((address_space(1))) unsigned int*)g,
      (__attribute__((address_space(3))) unsigned int*)(uintptr_t)l,
      16, 0, 0);
}

// ---------------- fp32 -> bf16 convert ----------------
__global__ __launch_bounds__(256)
void cvt_kernel(const float* __restrict__ in, __hip_bfloat16* __restrict__ out, int n) {
  int i = (blockIdx.x * 256 + threadIdx.x) * 4;
  if (i >= n) return;
  const float4 v = *(const float4*)(in + i);
  out[i + 0] = __float2bfloat16(v.x);
  out[i + 1] = __float2bfloat16(v.y);
  out[i + 2] = __float2bfloat16(v.z);
  out[i + 3] = __float2bfloat16(v.w);
}

// fused cvt of x (n0 elems) and w_qkv into one contiguous bf16 output
__global__ __launch_bounds__(256)
void cvt2_kernel(const float* __restrict__ in0, const float* __restrict__ in1,
                 __hip_bfloat16* __restrict__ out, int n0, int ntot) {
  int i = (blockIdx.x * 256 + threadIdx.x) * 4;
  if (i >= ntot) return;
  const float4 v = (i < n0) ? *(const float4*)(in0 + i)
                            : *(const float4*)(in1 + (i - n0));
  out[i + 0] = __float2bfloat16(v.x);
  out[i + 1] = __float2bfloat16(v.y);
  out[i + 2] = __float2bfloat16(v.z);
  out[i + 3] = __float2bfloat16(v.w);
}

#define MEMFENCE asm volatile("" ::: "memory")

// ===== QKV GEMM: 256M x 128N tile, 3-buffer, 2 blocks/CU (overlap via occupancy)
// 8 waves as 4M x 2N (per-wave 64x64, acc[4][4]). BK=32, depth-2 prefetch,
// counted vmcnt(3) (never 0 in steady loop), 1 barrier / K-step.
// XOR granule swizzle (R2-validated). XCD-chunked bijective swizzle: 768 blocks
// = 8 XCDs x 96; m fast within chunk -> B-panel stays L2-resident per XCD.
// Ledger: at step t top, outstanding = {t:3, t+1:3}; vmcnt(3) => tile t landed;
// barrier => all waves' tile-t landed AND t-1 reads retired => staging t+2
// into buf (t+2)%3 = (t-1)%3 safe.
__global__ __launch_bounds__(512, 4)
void gemm_qkvA(const __hip_bfloat16* __restrict__ A,
               const __hip_bfloat16* __restrict__ W,
               __hip_bfloat16* __restrict__ Qr,
               __hip_bfloat16* __restrict__ Kr,
               __hip_bfloat16* __restrict__ Vt)
{
  extern __shared__ __hip_bfloat16 sm[];   // 73728 B: 3 bufs x (A 16KB + B 8KB); +256 invf
  const int tid = threadIdx.x, lane = tid & 63, wave = tid >> 6;
  const int wr = wave >> 1, wc = wave & 1;               // 4M x 2N
  const int idx = blockIdx.y * 16 + blockIdx.x;          // grid (16,48)
  const int swz = (idx & 7) * 96 + (idx >> 3);           // XCD chunk (768%8==0)
  const int m0 = (swz & 15) << 8;                        // 16 m-tiles of 256
  const int n0 = (swz >> 4) << 7;                        // 48 n-tiles of 128
  const int lrow = lane & 15, dg = lane >> 4, lq4 = dg * 4;
  const int rslot = (dg ^ ((lrow >> 1) & 3)) * 8;
  const int arow = tid >> 2;
  const int ascol = ((tid & 3) ^ ((tid >> 3) & 3)) * 8;
  const __hip_bfloat16* aS0 = A + (size_t)(m0 + arow) * 2048 + ascol;
  const __hip_bfloat16* aS1 = A + (size_t)(m0 + 128 + arow) * 2048 + ascol;
  const __hip_bfloat16* bS0 = W + (size_t)(n0 + arow) * 2048 + ascol;
  float* invfp = (float*)((char*)sm + 73728);
  if (tid < 64) invfp[tid] = __expf(-(float)tid * 0.14391156831212787f);
  floatx4 acc[4][4] = {};

#define ASTG(TT) do { const int bo_ = ((TT) % 3) * 12288; const int kk_ = (TT) * 32; \
    gl2lds16(aS0 + kk_, &sm[bo_ + tid * 8]);                                   \
    gl2lds16(aS1 + kk_, &sm[bo_ + 4096 + tid * 8]);                            \
    gl2lds16(bS0 + kk_, &sm[bo_ + 8192 + tid * 8]); } while (0)

#define ACOMP(BO) do {                                                         \
    bf16x8 af[4], bfr[4];                                                      \
    _Pragma("unroll")                                                          \
    for (int mt = 0; mt < 4; mt++)                                             \
      af[mt] = *(const bf16x8*)&sm[(BO) + (wr * 64 + mt * 16 + lrow) * 32 + rslot]; \
    _Pragma("unroll")                                                          \
    for (int nt = 0; nt < 4; nt++)                                             \
      bfr[nt] = *(const bf16x8*)&sm[(BO) + 8192 + (wc * 64 + nt * 16 + lrow) * 32 + rslot]; \
    __builtin_amdgcn_s_setprio(1);                                             \
    _Pragma("unroll")                                                          \
    for (int mt = 0; mt < 4; mt++)                                             \
      _Pragma("unroll")                                                        \
      for (int nt = 0; nt < 4; nt++)                                           \
        acc[mt][nt] = __builtin_amdgcn_mfma_f32_16x16x32_bf16(af[mt], bfr[nt], acc[mt][nt], 0, 0, 0); \
    __builtin_amdgcn_s_setprio(0);                                             \
  } while (0)

  ASTG(0); ASTG(1);   // 6 VMEM in flight
  // 0x0073 = vmcnt(3) lgkm(0); 0x0070 = vmcnt(0) lgkm(0)
  for (int t = 0; t < 63; ++t) {
    MEMFENCE; __builtin_amdgcn_s_waitcnt(0x0073); MEMFENCE;
    __builtin_amdgcn_s_barrier(); MEMFENCE;
    if (t < 62) ASTG(t + 2);
    ACOMP((t % 3) * 12288);
  }
  MEMFENCE; __builtin_amdgcn_s_waitcnt(0x0070); MEMFENCE;
  __builtin_amdgcn_s_barrier(); MEMFENCE;
  ACOMP((63 % 3) * 12288);
#undef ACOMP
#undef ASTG

  // -------- epilogue: n-tile = 1 head; RoPE (Q/K) or transpose (V) --------
  const int seg = n0 >> 11;               // 0=Q 1=K 2=V
  const int h = (n0 & 2047) >> 7;
  const int b = m0 >> 11;
  const int seq0 = m0 & 2047;
  __syncthreads();                        // all K-loop LDS reads complete
  if (seg < 2) {                          // Csh[row 256][136]
#pragma unroll
    for (int mt = 0; mt < 4; mt++)
#pragma unroll
      for (int nt = 0; nt < 4; nt++)
#pragma unroll
        for (int r = 0; r < 4; r++)
          sm[(wr * 64 + mt * 16 + lq4 + r) * 136 + wc * 64 + nt * 16 + lrow] =
              __float2bfloat16(acc[mt][nt][r]);
  } else {                                // CshT[col 128][264]
#pragma unroll
    for (int mt = 0; mt < 4; mt++)
#pragma unroll
      for (int nt = 0; nt < 4; nt++)
#pragma unroll
        for (int r = 0; r < 4; r++)
          sm[(wc * 64 + nt * 16 + lrow) * 264 + wr * 64 + mt * 16 + lq4 + r] =
              __float2bfloat16(acc[mt][nt][r]);
  }
  __syncthreads();
  const float qs = (seg == 0) ? 0.08838834764831845f : 1.0f;
  if (seg < 2) {
    __hip_bfloat16* Out = seg ? Kr : Qr;
#pragma unroll
    for (int it = 0; it < 4; ++it) {
      const int task = tid + it * 512;    // 2048 tasks: 256 rows x 8 col-groups
      const int row = task >> 3;
      const int g8 = (task & 7) * 8;
      const int seq = seq0 + row;
      const float pos = (float)seq;
      const bf16x8 lo8 = *(const bf16x8*)&sm[row * 136 + g8];
      const bf16x8 hi8 = *(const bf16x8*)&sm[row * 136 + g8 + 64];
      alignas(16) __hip_bfloat16 lo[8], hi[8];
#pragma unroll
      for (int k = 0; k < 8; k++) {
        float sn, cs;
        __sincosf(pos * invfp[g8 + k], &sn, &cs);
        const float a = (float)lo8[k];
        const float bb2 = (float)hi8[k];
        lo[k] = __float2bfloat16((a * cs - bb2 * sn) * qs);
        hi[k] = __float2bfloat16((bb2 * cs + a * sn) * qs);
      }
      const size_t ob = ((size_t)((b * 16 + h) * 2048 + seq)) * 128;
      *(bf16x8*)&Out[ob + g8] = *(const bf16x8*)lo;
      *(bf16x8*)&Out[ob + g8 + 64] = *(const bf16x8*)hi;
    }
  } else {
#pragma unroll
    for (int it = 0; it < 8; ++it) {
      const int task = tid + it * 512;    // 4096 tasks: 128 d x 32 seq-groups
      const int col = task >> 5;
      const int sg = (task & 31) * 8;
      const bf16x8 v8 = *(const bf16x8*)&sm[col * 264 + sg];
      *(bf16x8*)&Vt[((size_t)((b * 16 + h) * 128 + col)) * 2048 + seq0 + sg] = v8;
    }
  }
}

// ============ O-proj GEMM: 256M x 128N tile, grid 16x16 (R5, unchanged) ========
__global__ __launch_bounds__(512, 2)
void gemm_o256(const __hip_bfloat16* __restrict__ A,
               const __hip_bfloat16* __restrict__ Wo,
               float* __restrict__ C)
{
  extern __shared__ __hip_bfloat16 sm[];   // 96KB: 4 bufs x (A 8192 + B 4096)
  const int tid = threadIdx.x, lane = tid & 63, wave = tid >> 6;
  const int wr = wave >> 2, wc = wave & 3;
  const int m0 = blockIdx.x << 8, n0 = blockIdx.y << 7;
  const int lrow = lane & 15, dg = lane >> 4, lq4 = dg * 4;
  const int rslot = (dg ^ ((lrow >> 1) & 3)) * 8;
  const int arow = tid >> 2;
  const int ascol = ((tid & 3) ^ ((tid >> 3) & 3)) * 8;
  const __hip_bfloat16* aS0 = A + (size_t)(m0 + arow) * 2048 + ascol;
  const __hip_bfloat16* aS1 = A + (size_t)(m0 + 128 + arow) * 2048 + ascol;
  const __hip_bfloat16* bS0 = Wo + (size_t)(n0 + arow) * 2048 + ascol;
  floatx4 acc[8][2] = {};

#define OSTAGE(TT) do { const int bb_ = (TT) & 3; const int kk_ = (TT) * 32;   \
    gl2lds16(aS0 + kk_, &sm[bb_ * 12288 + tid * 8]);                           \
    gl2lds16(aS1 + kk_, &sm[bb_ * 12288 + 4096 + tid * 8]);                    \
    gl2lds16(bS0 + kk_, &sm[bb_ * 12288 + 8192 + tid * 8]); } while (0)

#define OKSTEP(TT, WIMM, DOSTAGE) do {                                         \
    MEMFENCE; __builtin_amdgcn_s_waitcnt(WIMM); MEMFENCE;                      \
    __builtin_amdgcn_s_barrier(); MEMFENCE;                                    \
    const int bb = (TT) & 3;                                                   \
    if (DOSTAGE) OSTAGE((TT) + 3);                                             \
    bf16x8 af[8], bfr[2];                                                      \
    _Pragma("unroll")                                                          \
    for (int mt = 0; mt < 8; mt++)                                             \
      af[mt] = *(const bf16x8*)&sm[bb * 12288 + (wr * 128 + mt * 16 + lrow) * 32 + rslot]; \
    _Pragma("unroll")                                                          \
    for (int nt = 0; nt < 2; nt++)                                             \
      bfr[nt] = *(const bf16x8*)&sm[bb * 12288 + 8192 + (wc * 32 + nt * 16 + lrow) * 32 + rslot]; \
    __builtin_amdgcn_s_setprio(1);                                             \
    _Pragma("unroll")                                                          \
    for (int mt = 0; mt < 8; mt++)                                             \
      _Pragma("unroll")                                                        \
      for (int nt = 0; nt < 2; nt++)                                           \
        acc[mt][nt] = __builtin_amdgcn_mfma_f32_16x16x32_bf16(af[mt], bfr[nt], acc[mt][nt], 0, 0, 0); \
    __builtin_amdgcn_s_setprio(0);                                             \
  } while (0)

  OSTAGE(0); OSTAGE(1); OSTAGE(2);   // 9 VMEM in flight
  // 0x0076=vmcnt(6)lgkm(0)  0x0073=vmcnt(3)  0x0070=vmcnt(0)
  for (int t = 0; t < 61; ++t) OKSTEP(t, 0x0076, true);
  OKSTEP(61, 0x0076, false);
  OKSTEP(62, 0x0073, false);
  OKSTEP(63, 0x0070, false);
#undef OKSTEP
#undef OSTAGE

#pragma unroll
  for (int mt = 0; mt < 8; mt++)
#pragma unroll
    for (int nt = 0; nt < 2; nt++)
#pragma unroll
      for (int r = 0; r < 4; r++)
        C[(size_t)(m0 + wr * 128 + mt * 16 + lq4 + r) * 2048 +
          (n0 + wc * 32 + nt * 16 + lrow)] = acc[mt][nt][r];
}

// ---------------- sliding-window flash attention (R5-exact revert) ------------
#define KSTR 136
#define VSTR 72
__global__ __launch_bounds__(512, 4)
void attn_swa(const __hip_bfloat16* __restrict__ Qr, const __hip_bfloat16* __restrict__ Kr,
              const __hip_bfloat16* __restrict__ Vt, __hip_bfloat16* __restrict__ Out)
{
  __shared__ __hip_bfloat16 Ks[64 * KSTR];
  __shared__ __hip_bfloat16 Vs[128 * VSTR];
  __shared__ __hip_bfloat16 Pb[8][16 * VSTR];
  const int qt = blockIdx.x, bh = blockIdx.y;
  const int tid = threadIdx.x, lane = tid & 63, wave = tid >> 6;
  const int lrow = lane & 15, lk = (lane >> 4) * 8, lq4 = (lane >> 4) * 4;
  const int i0 = qt * 128;
  const float NEG_INF = -__builtin_inff();
  const __hip_bfloat16* Qh = Qr + (size_t)bh * 2048 * 128;
  const __hip_bfloat16* Kh = Kr + (size_t)bh * 2048 * 128;
  const __hip_bfloat16* Vh = Vt + (size_t)bh * 128 * 2048;

  const int ck0 = tid, ck1 = tid + 512;
  const int kr0 = ck0 >> 4, kg0 = (ck0 & 15) * 8;
  const int kr1 = ck1 >> 4, kg1 = (ck1 & 15) * 8;
  const int cv0 = tid, cv1 = tid + 512;
  const int vd0 = cv0 >> 3, vc0 = (cv0 & 7) * 8;
  const int vd1 = cv1 >> 3, vc1 = (cv1 & 7) * 8;

  const int iw = i0 + wave * 16 + lrow;
  bf16x8 qf[4];
#pragma unroll
  for (int ks = 0; ks < 4; ks++)
    qf[ks] = *(const bf16x8*)&Qh[(size_t)iw * 128 + ks * 32 + lk];

  floatx4 accO[8] = {};
  float m_i = NEG_INF, l_i = 0.f;
  const int imin = i0 + wave * 16;
  const int lo = i0 - 511;
  const int jt_lo = (lo > 0 ? lo : 0) >> 6;
  const int jt_hi = (i0 + 127) >> 6;

  int j0n = jt_lo * 64;
  int4 rk0 = *(const int4*)&Kh[(size_t)(j0n + kr0) * 128 + kg0];
  int4 rk1 = *(const int4*)&Kh[(size_t)(j0n + kr1) * 128 + kg1];
  int4 rv0 = *(const int4*)&Vh[(size_t)vd0 * 2048 + j0n + vc0];
  int4 rv1 = *(const int4*)&Vh[(size_t)vd1 * 2048 + j0n + vc1];

  for (int jt = jt_lo; jt <= jt_hi; jt++) {
    const int j0 = jt * 64;
    __syncthreads();
    *(int4*)&Ks[kr0 * KSTR + kg0] = rk0;
    *(int4*)&Ks[kr1 * KSTR + kg1] = rk1;
    *(int4*)&Vs[vd0 * VSTR + vc0] = rv0;
    *(int4*)&Vs[vd1 * VSTR + vc1] = rv1;
    if (jt < jt_hi) {
      const int jn = j0 + 64;
      rk0 = *(const int4*)&Kh[(size_t)(jn + kr0) * 128 + kg0];
      rk1 = *(const int4*)&Kh[(size_t)(jn + kr1) * 128 + kg1];
      rv0 = *(const int4*)&Vh[(size_t)vd0 * 2048 + jn + vc0];
      rv1 = *(const int4*)&Vh[(size_t)vd1 * 2048 + jn + vc1];
    }
    asm volatile("" ::: "memory");
    __builtin_amdgcn_s_waitcnt(0xC07F);
    __builtin_amdgcn_s_barrier();
    asm volatile("" ::: "memory");

    floatx4 s[4] = {};
#pragma unroll
    for (int nt = 0; nt < 4; nt++) {
      const int krow = (nt * 16 + lrow) * KSTR;
#pragma unroll
      for (int ks = 0; ks < 4; ks++) {
        const bf16x8 kf = *(const bf16x8*)&Ks[krow + ks * 32 + lk];
        s[nt] = __builtin_amdgcn_mfma_f32_16x16x32_bf16(kf, qf[ks], s[nt], 0, 0, 0);
      }
    }
    const bool full = (j0 + 63 <= imin) && (j0 >= imin + 15 - 511);
    float rmax = NEG_INF;
    if (full) {
#pragma unroll
      for (int nt = 0; nt < 4; nt++)
#pragma unroll
        for (int r = 0; r < 4; r++) rmax = fmaxf(rmax, s[nt][r]);
    } else {
#pragma unroll
      for (int nt = 0; nt < 4; nt++) {
#pragma unroll
        for (int r = 0; r < 4; r++) {
          const int j = j0 + nt * 16 + lq4 + r;
          const float sv = ((j <= iw) && (j > iw - 512)) ? s[nt][r] : NEG_INF;
          s[nt][r] = sv;
          rmax = fmaxf(rmax, sv);
        }
      }
    }
    rmax = fmaxf(rmax, __shfl_xor(rmax, 16));
    rmax = fmaxf(rmax, __shfl_xor(rmax, 32));
    const float mnew = fmaxf(m_i, rmax);
    const float alpha = __expf(fminf(m_i - mnew, 0.f));
    m_i = mnew;
    float rs = 0.f;
    if (full) {
#pragma unroll
      for (int nt = 0; nt < 4; nt++)
#pragma unroll
        for (int r = 0; r < 4; r++) {
          const float p = __expf(s[nt][r] - mnew);
          s[nt][r] = p;
          rs += p;
        }
    } else {
#pragma unroll
      for (int nt = 0; nt < 4; nt++)
#pragma unroll
        for (int r = 0; r < 4; r++) {
          const float sv = s[nt][r];
          const float p = (sv == NEG_INF) ? 0.f : __expf(sv - mnew);
          s[nt][r] = p;
          rs += p;
        }
    }
    rs += __shfl_xor(rs, 16);
    rs += __shfl_xor(rs, 32);
    l_i = l_i * alpha + rs;
#pragma unroll
    for (int dt = 0; dt < 8; dt++) accO[dt] *= alpha;
#pragma unroll
    for (int nt = 0; nt < 4; nt++) {
      alignas(8) __hip_bfloat16 p4[4];
#pragma unroll
      for (int r = 0; r < 4; r++) p4[r] = __float2bfloat16(s[nt][r]);
      *(uint64_t*)&Pb[wave][lrow * VSTR + nt * 16 + lq4] = *(const uint64_t*)p4;
    }
    bf16x8 pf[2];
#pragma unroll
    for (int jf = 0; jf < 2; jf++)
      pf[jf] = *(const bf16x8*)&Pb[wave][lrow * VSTR + jf * 32 + lk];
#pragma unroll
    for (int dt = 0; dt < 8; dt++) {
      const int vrow = (dt * 16 + lrow) * VSTR;
#pragma unroll
      for (int jf = 0; jf < 2; jf++) {
        const bf16x8 vf = *(const bf16x8*)&Vs[vrow + jf * 32 + lk];
        accO[dt] = __builtin_amdgcn_mfma_f32_16x16x32_bf16(vf, pf[jf], accO[dt], 0, 0, 0);
      }
    }
  }
  const int b = bh >> 4, h = bh & 15;
  const float inv_l = 1.0f / l_i;
  const size_t rowb = ((size_t)(b * 2048 + iw)) * 2048 + h * 128;
#pragma unroll
  for (int dt = 0; dt < 8; dt++) {
    alignas(8) __hip_bfloat16 o4[4];
#pragma unroll
    for (int r = 0; r < 4; r++) o4[r] = __float2bfloat16(accO[dt][r] * inv_l);
    *(uint64_t*)&Out[rowb + dt * 16 + lq4] = *(const uint64_t*)o4;
  }
}

// ---------------- launch ----------------
extern "C" void kernel_launch(void* const* d_in, const int* in_sizes, int n_in,
                              void* d_out, int out_size, void* d_ws, size_t ws_size,
                              hipStream_t stream)
{
  const float* x = (const float*)d_in[0];      // [2,2048,2048]
  const float* w_qkv = (const float*)d_in[1];  // [6144,2048]
  const float* w_o = (const float*)d_in[2];    // [2048,2048]
  float* y = (float*)d_out;                    // [2,2048,2048] fp32
  char* ws = (char*)d_ws;

  const size_t SZ_X = 16777216;     // 4096*2048*2 B
  const size_t SZ_WQKV = 25165824;  // 6144*2048*2 B
  const size_t SZ_Q = 16777216;     // 32*2048*128*2 B

  __hip_bfloat16* xb = (__hip_bfloat16*)(ws);            // x bf16; later attn out
  __hip_bfloat16* wqkvb = (__hip_bfloat16*)(ws + SZ_X);  // w_qkv bf16; later w_o bf16
  __hip_bfloat16* Qr = (__hip_bfloat16*)(ws + SZ_X + SZ_WQKV);
  __hip_bfloat16* Kr = (__hip_bfloat16*)(ws + SZ_X + SZ_WQKV + SZ_Q);
  __hip_bfloat16* Vt = (__hip_bfloat16*)(ws + SZ_X + SZ_WQKV + 2 * SZ_Q);

  static bool s_attr_done = false;
  if (!s_attr_done) {
    hipFuncSetAttribute((const void*)gemm_qkvA,
                        hipFuncAttributeMaxDynamicSharedMemorySize, 73984);
    hipFuncSetAttribute((const void*)gemm_o256,
                        hipFuncAttributeMaxDynamicSharedMemorySize, 98304);
    s_attr_done = true;
  }

  // x + w_qkv converted in one launch (outputs are contiguous in ws)
  cvt2_kernel<<<dim3(20480), dim3(256), 0, stream>>>(x, w_qkv, xb, 8388608, 20971520);
  gemm_qkvA<<<dim3(16, 48), dim3(512), 73984, stream>>>(xb, wqkvb, Qr, Kr, Vt);
  attn_swa<<<dim3(16, 32), dim3(512), 0, stream>>>(Qr, Kr, Vt, xb /*attn_out*/);
  cvt_kernel<<<dim3(4096), dim3(256), 0, stream>>>(w_o, wqkvb, 4194304);
  gemm_o256<<<dim3(16, 16), dim3(512), 98304, stream>>>(xb, wqkvb, y);
}